// Round 9
// baseline (2010.082 us; speedup 1.0000x reference)
//
#include <hip/hip_runtime.h>
#include <hip/hip_bf16.h>

#pragma clang fp contract(off)

#define TT 512
#define CC 256
#define TPAD 257
#define INFV 1e9f

__device__ __forceinline__ unsigned long long packkey(float v, unsigned c) {
  return ((unsigned long long)__float_as_uint(v) << 32) | (unsigned long long)c;
}

__device__ __forceinline__ unsigned long long wave_min_u64(unsigned long long k) {
#pragma unroll
  for (int off = 32; off >= 1; off >>= 1) {
    unsigned long long o = __shfl_xor(k, off, 64);
    if (o < k) k = o;
  }
  return k;
}

// ---------------- Phase 1: distance matrix + initial row-min keys ----------------
// (unchanged — measured ~515 us, absmax 0.0; agglom changes isolated)
__device__ void load_norm_tile(const float* __restrict__ xb, int rowBase,
                               float (*S)[TPAD], double* part, int tid) {
  for (int idx = tid; idx < 64 * CC; idx += 256) {
    int r = idx >> 8;
    int c = idx & (CC - 1);
    S[r][c] = xb[(size_t)(rowBase + r) * CC + c];
  }
  __syncthreads();
  {
    int r = tid >> 2, p = tid & 3;
    double s = 0.0;
    int c0 = p * 64;
    for (int c = 0; c < 64; ++c) {
      double v = (double)S[r][c0 + c];
      s = fma(v, v, s);
    }
    part[tid] = s;
  }
  __syncthreads();
  if ((tid & 3) == 0) {
    double tot = part[tid] + part[tid + 1] + part[tid + 2] + part[tid + 3];
    part[tid] = sqrt(tot) + 1e-8;  // norm + EPS, in f64
  }
  __syncthreads();
  for (int idx = tid; idx < 64 * CC; idx += 256) {
    int r = idx >> 8;
    int c = idx & (CC - 1);
    S[r][c] = (float)((double)S[r][c] / part[r << 2]);
  }
  __syncthreads();
}

__global__ __launch_bounds__(256) void build_dist_kernel(
    const float* __restrict__ x, float* __restrict__ dall,
    unsigned long long* __restrict__ rkall) {
  __shared__ float A[64][TPAD];
  __shared__ float Bs[64][TPAD];
  __shared__ double part[256];
  __shared__ unsigned long long rkl[64];

  int ta = blockIdx.x;   // row tile 0..7
  int b  = blockIdx.y;   // batch
  const float* xb = x + (size_t)b * TT * CC;
  float* d = dall + (size_t)b * TT * TT;
  int tid = threadIdx.x;
  if (tid < 64) rkl[tid] = ~0ull;
  load_norm_tile(xb, ta * 64, A, part, tid);

  int ty = tid & 15;   // col group (contiguous cols -> coalesced float4 stores)
  int tx = tid >> 4;   // row group
  for (int tb = 0; tb < 8; ++tb) {
    __syncthreads();   // previous Bs consumers done
    load_norm_tile(xb, tb * 64, Bs, part, tid);
    double acc[4][4];
#pragma unroll
    for (int ia = 0; ia < 4; ++ia)
#pragma unroll
      for (int ib = 0; ib < 4; ++ib) acc[ia][ib] = 0.0;
    for (int k = 0; k < CC; ++k) {
      double av[4], bv[4];
#pragma unroll
      for (int ia = 0; ia < 4; ++ia) av[ia] = (double)A[4 * tx + ia][k];
#pragma unroll
      for (int ib = 0; ib < 4; ++ib) bv[ib] = (double)Bs[4 * ty + ib][k];
#pragma unroll
      for (int ia = 0; ia < 4; ++ia)
#pragma unroll
        for (int ib = 0; ib < 4; ++ib)
          acc[ia][ib] = fma(av[ia], bv[ib], acc[ia][ib]);
    }
#pragma unroll
    for (int ia = 0; ia < 4; ++ia) {
      int gr = ta * 64 + 4 * tx + ia;
      int gcBase = tb * 64 + 4 * ty;
      float vt[4];
      unsigned long long key = ~0ull;
#pragma unroll
      for (int ib = 0; ib < 4; ++ib) {
        int gc = gcBase + ib;
        float v = (gr == gc) ? INFV : (float)(1.0 - acc[ia][ib]);
        vt[ib] = v;
        unsigned long long kk = packkey(v, (unsigned)gc);
        if (kk < key) key = kk;
      }
      *(float4*)(&d[(size_t)gr * TT + gcBase]) =
          make_float4(vt[0], vt[1], vt[2], vt[3]);
#pragma unroll
      for (int off = 1; off < 16; off <<= 1) {
        unsigned long long o = __shfl_xor(key, off, 64);
        if (o < key) key = o;
      }
      if (ty == 0) atomicMin(&rkl[4 * tx + ia], key);
    }
  }
  __syncthreads();
  if (tid < 64) rkall[(size_t)b * TT + ta * 64 + tid] = rkl[tid];
}

// ---------------- Phase 2: agglomerative merging, 4 waves / batch, 2 barriers/iter ----
// Memory discipline as round 7 (PASSED, absmax 0.0): col-j kill stores keep global
// memory the full truth. Schedule:
//  Phase A: final argmin from pm[] partials (computed END of prev Phase B);
//           issue row i/j loads; flag own rows; WAVE-LOCAL ballot (wave rescans
//           only its own 128 rows -> no cross-wave list, no atomics); issue up
//           to 2 rescan preloads/wave (concurrent with row i/j latency);
//           compute w, nvs, pmi[] partials.                               B1
//  Phase B: stores (row i, col-i scatter, col-j kills); OWNER threads finalize
//           rk[i]/sizes[i] (fold pmi) and rk[j]/sizes[j]; lazy+assign; patch-fold
//           preloaded rescan rows (patch c==i -> nvs[rr], c==j -> INFV: the only
//           two addresses racing with this iter's stores; dword stores don't
//           tear, old-or-new both overwritten); leftover rescans via direct
//           loads + same patch; wave folds own 128 rows -> pm[w].         B2
// Merge arithmetic / key packing / tie-breaks bitwise-identical to rounds 2/7.
__global__ __launch_bounds__(256) void agglom_kernel(
    const int* __restrict__ ncp, float* __restrict__ dall,
    const unsigned long long* __restrict__ rkall, int* __restrict__ outp) {
  __shared__ unsigned long long rk[TT];
  __shared__ float sizes[TT];
  __shared__ float nvs[TT];
  __shared__ int assign[TT];
  __shared__ int rankArr[TT];
  __shared__ unsigned long long pm[4];    // per-wave argmin partials
  __shared__ unsigned long long pmi[4];   // per-wave new-row-i min partials
  __shared__ int wsum[4];

  int b = blockIdx.x;
  int tid = threadIdx.x;
  int lane = tid & 63;
  int w = tid >> 6;
  int wb = w * 128;                       // wave's owned row range [wb, wb+128)
  float* d = dall + (size_t)b * TT * TT;
  int rA = tid * 2, rB = rA + 1;          // this thread's owned rows / cols

  rk[rA] = rkall[(size_t)b * TT + rA];
  rk[rB] = rkall[(size_t)b * TT + rB];
  sizes[rA] = 1.0f; sizes[rB] = 1.0f;
  assign[rA] = rA;  assign[rB] = rB;
  int K = ncp[0];
  if (K > TT) K = TT;
  if (K < 1) K = 1;
  int nm = TT - K;
  __syncthreads();

  // initial pm[] partials (own 128 rows per wave)
  {
    unsigned long long kA =
        (rk[rA] & 0xFFFFFFFF00000000ull) | (unsigned long long)(unsigned)rA;
    unsigned long long kB =
        (rk[rB] & 0xFFFFFFFF00000000ull) | (unsigned long long)(unsigned)rB;
    unsigned long long bst = kA < kB ? kA : kB;
    bst = wave_min_u64(bst);
    if (lane == 0) pm[w] = bst;
  }
  __syncthreads();

  for (int iter = 0; iter < nm; ++iter) {
    // ================= Phase A =================
    unsigned long long best = pm[0];
    if (pm[1] < best) best = pm[1];
    if (pm[2] < best) best = pm[2];
    if (pm[3] < best) best = pm[3];
    int i = (int)(best & 0xFFFFFFFFull);   // smallest flat index => row wins tie
    int j = (int)(rk[i] & 0xFFFFFFFFull);  // its first-min column (j > i)
    float ni = sizes[i], nj = sizes[j];
    float denom = ni + nj;

    // issue row i/j loads first (oldest in vmcnt queue)
    float2 a2 = *(const float2*)(d + (size_t)i * TT + rA);
    float2 b2 = *(const float2*)(d + (size_t)j * TT + rA);

    // flag own rows whose cached min points at i or j (pre-update rk, LDS only)
    unsigned fl = 0;
    {
      if (rA != i && rA != j && sizes[rA] > 0.0f) {
        unsigned c = (unsigned)(rk[rA] & 0xFFFFFFFFull);
        if (c == (unsigned)i || c == (unsigned)j) fl |= 1u;
      }
      if (rB != i && rB != j && sizes[rB] > 0.0f) {
        unsigned c = (unsigned)(rk[rB] & 0xFFFFFFFFull);
        if (c == (unsigned)i || c == (unsigned)j) fl |= 2u;
      }
    }
    unsigned long long mm0 = __ballot(fl & 1u);   // wave-local rescan masks
    unsigned long long mm1 = __ballot(fl & 2u);

    // preload up to 2 rescan rows per wave (concurrent with row i/j latency)
    int er0 = -1, er1 = -1;
    float4 pa0, pb0, pa1, pb1;
    if (mm0) { int l = __ffsll(mm0) - 1; mm0 &= mm0 - 1; er0 = wb + 2 * l; }
    else if (mm1) { int l = __ffsll(mm1) - 1; mm1 &= mm1 - 1; er0 = wb + 2 * l + 1; }
    if (er0 >= 0) {
      const float4* p = (const float4*)(d + (size_t)er0 * TT);
      pa0 = p[lane * 2]; pb0 = p[lane * 2 + 1];
    }
    if (mm0) { int l = __ffsll(mm0) - 1; mm0 &= mm0 - 1; er1 = wb + 2 * l; }
    else if (mm1) { int l = __ffsll(mm1) - 1; mm1 &= mm1 - 1; er1 = wb + 2 * l + 1; }
    if (er1 >= 0) {
      const float4* p = (const float4*)(d + (size_t)er1 * TT);
      pa1 = p[lane * 2]; pb1 = p[lane * 2 + 1];
    }

    // newrow = (ni*d[i] + nj*d[j]) / (ni+nj)  [contract(off): mul,mul,add,div]
    float v0 = (ni * a2.x + nj * b2.x) / denom;
    float v1 = (ni * a2.y + nj * b2.y) / denom;
    float w0 = (rA == i || rA == j) ? INFV : v0;
    float w1 = (rB == i || rB == j) ? INFV : v1;
    nvs[rA] = w0; nvs[rB] = w1;
    unsigned long long ik = packkey(w0, (unsigned)rA);
    unsigned long long ik2 = packkey(w1, (unsigned)rB);
    if (ik2 < ik) ik = ik2;
    ik = wave_min_u64(ik);
    if (lane == 0) pmi[w] = ik;
    __syncthreads();                                   // B1 (nvs, pmi visible)

    // ================= Phase B =================
    // stores: row i (coalesced float2), col-i scatter, col-j kill
    *(float2*)(d + (size_t)i * TT + rA) = make_float2(w0, w1);
    d[(size_t)rA * TT + i] = w0;
    d[(size_t)rB * TT + i] = w1;
    d[(size_t)rA * TT + j] = INFV;
    d[(size_t)rB * TT + j] = INFV;

    // owner threads finalize merged/killed rows (replaces tid0 + extra barrier)
    if (tid == (i >> 1)) {
      unsigned long long ikey = pmi[0];
      if (pmi[1] < ikey) ikey = pmi[1];
      if (pmi[2] < ikey) ikey = pmi[2];
      if (pmi[3] < ikey) ikey = pmi[3];
      rk[i] = ikey;
      sizes[i] = denom;
    }
    if (tid == (j >> 1)) {
      rk[j] = packkey(INFV, 0xFFFFFFFFu);
      sizes[j] = 0.0f;
    }

    // lazy min-update (unflagged rows: candidate new min at column i) + assign
#pragma unroll
    for (int t = 0; t < 2; ++t) {
      int r = rA + t;
      if (!((fl >> t) & 1u) && r != i && r != j && sizes[r] > 0.0f) {
        unsigned long long cur = rk[r];
        unsigned long long nk = packkey(nvs[r], (unsigned)i);
        if (nk < cur) rk[r] = nk;          // equal-val smaller-col handled
      }
      if (assign[r] == j) assign[r] = i;
    }

    // rescan: patch preloaded rows (c==i -> nvs[rr], c==j -> INFV; everything
    // else is memory truth thanks to kill stores), fold, write rk
    {
      int cb = lane * 8;
      if (er0 >= 0) {
        float pv = nvs[er0];
        unsigned long long key = ~0ull, kk;
#pragma unroll
        for (int t = 0; t < 8; ++t) {
          int c = cb + t;
          float e = t < 4 ? (&pa0.x)[t] : (&pb0.x)[t - 4];
          e = (c == i) ? pv : ((c == j) ? INFV : e);
          kk = packkey(e, (unsigned)c); if (kk < key) key = kk;
        }
        key = wave_min_u64(key);
        if (lane == 0) rk[er0] = key;
      }
      if (er1 >= 0) {
        float pv = nvs[er1];
        unsigned long long key = ~0ull, kk;
#pragma unroll
        for (int t = 0; t < 8; ++t) {
          int c = cb + t;
          float e = t < 4 ? (&pa1.x)[t] : (&pb1.x)[t - 4];
          e = (c == i) ? pv : ((c == j) ? INFV : e);
          kk = packkey(e, (unsigned)c); if (kk < key) key = kk;
        }
        key = wave_min_u64(key);
        if (lane == 0) rk[er1] = key;
      }
      // leftovers (>2 rescans on one wave, rare): direct loads + same patch.
      // Loads may race this iter's col-i/col-j stores, but those two addresses
      // are patched regardless, and dword stores don't tear.
      while (mm0 | mm1) {
        int rr;
        if (mm0) { int l = __ffsll(mm0) - 1; mm0 &= mm0 - 1; rr = wb + 2 * l; }
        else     { int l = __ffsll(mm1) - 1; mm1 &= mm1 - 1; rr = wb + 2 * l + 1; }
        const float4* p = (const float4*)(d + (size_t)rr * TT);
        float4 x0 = p[lane * 2], x1 = p[lane * 2 + 1];
        float pv = nvs[rr];
        unsigned long long key = ~0ull, kk;
#pragma unroll
        for (int t = 0; t < 8; ++t) {
          int c = cb + t;
          float e = t < 4 ? (&x0.x)[t] : (&x1.x)[t - 4];
          e = (c == i) ? pv : ((c == j) ? INFV : e);
          kk = packkey(e, (unsigned)c); if (kk < key) key = kk;
        }
        key = wave_min_u64(key);
        if (lane == 0) rk[rr] = key;
      }
    }

    // wave folds its own 128 rows -> pm[w] for NEXT iteration's argmin.
    // All rk updates to own rows happened in this wave (owner writes, lazy,
    // lane0 rescan writes) -> same-wave LDS ordering suffices.
    {
      unsigned long long kA =
          (rk[rA] & 0xFFFFFFFF00000000ull) | (unsigned long long)(unsigned)rA;
      unsigned long long kB =
          (rk[rB] & 0xFFFFFFFF00000000ull) | (unsigned long long)(unsigned)rB;
      unsigned long long bst = kA < kB ? kA : kB;
      bst = wave_min_u64(bst);
      if (lane == 0) pm[w] = bst;
    }
    __syncthreads();                                   // B2 (stores drained, pm ready)
  }

  // ---- canonical relabel: assign[t] == min original index of t's cluster
  int f0 = (assign[rA] == rA) ? 1 : 0;
  int f1 = (assign[rB] == rB) ? 1 : 0;
  int c = f0 + f1;
  int incl = c;
#pragma unroll
  for (int off = 1; off < 64; off <<= 1) {
    int o = __shfl_up(incl, (unsigned)off, 64);
    if (lane >= off) incl += o;
  }
  if (lane == 63) wsum[w] = incl;
  __syncthreads();
  int base = incl - c;
  for (int q = 0; q < w; ++q) base += wsum[q];
  if (f0) rankArr[rA] = base;
  if (f1) rankArr[rB] = base + f0;
  __syncthreads();
  outp[(size_t)b * TT + rA] = rankArr[assign[rA]];
  outp[(size_t)b * TT + rB] = rankArr[assign[rB]];
}

extern "C" void kernel_launch(void* const* d_in, const int* in_sizes, int n_in,
                              void* d_out, int out_size, void* d_ws, size_t ws_size,
                              hipStream_t stream) {
  const float* x = (const float*)d_in[0];
  const int* ncp = (const int*)d_in[1];
  int B = in_sizes[0] / (TT * CC);
  float* dall = (float*)d_ws;                                   // B * 512*512 f32 (64 MiB)
  unsigned long long* rkall =
      (unsigned long long*)((char*)d_ws + (size_t)B * TT * TT * sizeof(float));
  int* outp = (int*)d_out;

  dim3 g1(TT / 64, B);
  build_dist_kernel<<<g1, 256, 0, stream>>>(x, dall, rkall);
  agglom_kernel<<<B, 256, 0, stream>>>(ncp, dall, rkall, outp);
}